// Round 9
// baseline (308.470 us; speedup 1.0000x reference)
//
#include <hip/hip_runtime.h>

#define T_DIM 512
#define C_DIM 48
#define BPS   48          // bp row stride; 16-lane spill into next row is benign (see store)
#define CH    4           // global-prefetch chunk

#if __has_builtin(__builtin_amdgcn_readlane)
#define READLANE_I(v, l) __builtin_amdgcn_readlane((v), (l))
#else
#define READLANE_I(v, l) __shfl((v), (l), 64)
#endif

// Compiler-level ordering fence for single-wave LDS communication.
#if __has_builtin(__builtin_amdgcn_wave_barrier)
#define WAVE_SYNC() do { __asm__ __volatile__("" ::: "memory"); __builtin_amdgcn_wave_barrier(); } while (0)
#else
#define WAVE_SYNC() __asm__ __volatile__("" ::: "memory")
#endif

// One DPP max-reduce step: lanes with invalid source keep their own value
// (old = v, bound_ctrl = false), so max semantics are preserved.
#define DPP_MAX_STEP(V_, CTRL_) do {                                          \
    int o_ = __builtin_amdgcn_update_dpp(__float_as_int(V_),                  \
                                         __float_as_int(V_),                  \
                                         (CTRL_), 0xF, 0xF, false);           \
    V_ = fmaxf(V_, __int_as_float(o_));                                       \
} while (0)

// Full-wave f32 max (VALU-only, no LDS pipe): row_shr 1/2/4/8 then
// row_bcast:15, row_bcast:31; lane 63 holds the wave max -> broadcast.
// Lanes 48-63 hold duplicates of lane 47 in all uses here (harmless for max).
__device__ __forceinline__ float wave_max_f(float v) {
    DPP_MAX_STEP(v, 0x111);   // row_shr:1
    DPP_MAX_STEP(v, 0x112);   // row_shr:2
    DPP_MAX_STEP(v, 0x114);   // row_shr:4
    DPP_MAX_STEP(v, 0x118);   // row_shr:8
    DPP_MAX_STEP(v, 0x142);   // row_bcast:15
    DPP_MAX_STEP(v, 0x143);   // row_bcast:31
    return __int_as_float(READLANE_I(__float_as_int(v), 63));
}

__global__ __launch_bounds__(64) void crf_viterbi(
    const float* __restrict__ pot,     // [B][T][C]
    const int*   __restrict__ seqlen,  // [B][1]
    const float* __restrict__ trans,   // [C][C]
    float*       __restrict__ out)     // [B][T][C] one-hot f32
{
    const int b   = blockIdx.x;
    const int tid = threadIdx.x;
    const int jj  = (tid < C_DIM) ? tid : (C_DIM - 1);  // clamped for safe loads

    __shared__ __align__(16) float trl[C_DIM * C_DIM];   // transitions, row-major
    __shared__ unsigned char bp[T_DIM * BPS];            // rows 1..L-1 used
    __shared__ __align__(4) unsigned char tags[T_DIM];
    __shared__ __align__(16) float fsc[64];              // final scores

    const float* potb = pot + (size_t)b * (T_DIM * C_DIM);
    const int L   = seqlen[b];          // in [1, 511]
    const int thi = L - 1;

    // ---- stage transitions into LDS (coalesced) + compute tmax = max|Tr| ----
    float tm = 0.0f;
    for (int i = tid; i < C_DIM * C_DIM; i += 64) {      // 36 iters exactly
        float v = trans[i];
        trl[i] = v;
        tm = fmaxf(tm, fabsf(v));
    }
    const float tmax = wave_max_f(tm);                   // uniform
    const float nC5 = -(5.0f * tmax + 1e-3f);            // steady-state margin
    const float nC2 = -(2.0f * tmax + 1e-3f);            // prologue margin
    WAVE_SYNC();                                         // trl visible (same wave)

    // ---- init: lane j holds s(0)[j]; thr(1) from exact s_max(0) ----
    float ns = potb[jj];
    float vthr = wave_max_f(ns) + nC2;

    const float* pp = potb + jj;

    // ---- prefetch pot rows + per-row (pmax + nC5) (input-only, off the chain) ----
    float pb[CH];
    float pmr5[CH];
#pragma unroll
    for (int k = 0; k < CH; ++k) {
        int tt = 1 + k; if (tt > T_DIM - 1) tt = T_DIM - 1;
        pb[k] = pp[tt * C_DIM];
    }
#pragma unroll
    for (int k = 0; k < CH; ++k) pmr5[k] = wave_max_f(pb[k]) + nC5;

    for (int t0 = 1; t0 < L; t0 += CH) {
        float nb[CH];
#pragma unroll
        for (int k = 0; k < CH; ++k) {
            int tt = t0 + CH + k; if (tt > T_DIM - 1) tt = T_DIM - 1;
            nb[k] = pp[tt * C_DIM];
        }
#pragma unroll
        for (int k = 0; k < CH; ++k) {
            const int t = t0 + k;
            if (t >= L) break;           // wave-uniform branch
            // ---- candidate-pruned Viterbi step (batched evaluation) ----
            // Winner i* for any j satisfies s_i* >= s_max - 2*tmax; vthr is a
            // proven lower bound of s_max - 2*tmax - slack  => superset mask.
            unsigned long long mm =
                __ballot(ns >= vthr) & 0x0000FFFFFFFFFFFFull;
            if (!mm) mm = 0x0000FFFFFFFFFFFFull;         // defensive: full argmax
            // extract up to 4 candidates (ascending); duplicate last if fewer.
            const int c0 = (int)__builtin_ctzll(mm);
            const unsigned long long m1 = mm & (mm - 1);
            const int c1 = m1 ? (int)__builtin_ctzll(m1) : c0;
            const unsigned long long m2 = m1 & (m1 - 1);
            const int c2 = m2 ? (int)__builtin_ctzll(m2) : c1;
            const unsigned long long m3 = m2 & (m2 - 1);
            const int c3 = m3 ? (int)__builtin_ctzll(m3) : c2;
            unsigned long long rest = m3 & (m3 - 1);
            // batch: 4 readlanes (independent) + 4 LDS reads (one wait)
            const float s0 = __int_as_float(READLANE_I(__float_as_int(ns), c0));
            const float s1 = __int_as_float(READLANE_I(__float_as_int(ns), c1));
            const float s2 = __int_as_float(READLANE_I(__float_as_int(ns), c2));
            const float s3 = __int_as_float(READLANE_I(__float_as_int(ns), c3));
            const float g0 = trl[c0 * C_DIM + jj];
            const float g1 = trl[c1 * C_DIM + jj];
            const float g2 = trl[c2 * C_DIM + jj];
            const float g3 = trl[c3 * C_DIM + jj];
            const float v0 = s0 + g0;                    // exact same add as ref
            const float v1 = s1 + g1;
            const float v2 = s2 + g2;
            const float v3 = s3 + g3;
            // ascending-index strict-> select == first-occurrence argmax;
            // duplicated candidates produce equal values and lose the tie.
            float mx = v0; int wi = c0;
            if (v1 > mx) { mx = v1; wi = c1; }
            if (v2 > mx) { mx = v2; wi = c2; }
            if (v3 > mx) { mx = v3; wi = c3; }
            while (rest) {                               // rare (>4 candidates)
                int c = (int)__builtin_ctzll(rest); rest &= rest - 1;
                float s = __int_as_float(READLANE_I(__float_as_int(ns), c));
                float cv = s + trl[c * C_DIM + jj];
                if (cv > mx) { mx = cv; wi = c; }
            }
            // bp store: all 64 lanes; lanes 48-63 spill into row t+1 cols 0-15,
            // which is overwritten next step (or is row thi+1 <= 511: never read).
            bp[t * BPS + tid] = (unsigned char)wi;
            ns   = mx + pb[k];                           // exact same add as ref
            vthr = mx + pmr5[k];                         // thr(t+1), per-lane valid
        }
        // next-chunk pmax reduces (nb latency already covered by the 4 steps)
        float pmn5[CH];
#pragma unroll
        for (int k = 0; k < CH; ++k) pmn5[k] = wave_max_f(nb[k]) + nC5;
#pragma unroll
        for (int k = 0; k < CH; ++k) { pb[k] = nb[k]; pmr5[k] = pmn5[k]; }
    }

    // publish final scores
    fsc[tid] = ns;
    WAVE_SYNC();
    __syncthreads();   // phase boundary (single wave; cheap)

    // last_tag = argmax over final scores (uniform LDS reads, broadcast)
    const float* fs = fsc;
    float bv = fs[0];
    int   bi = 0;
#pragma unroll
    for (int i = 1; i < C_DIM; ++i) {
        float v = fs[i];
        if (v > bv) { bv = v; bi = i; }
    }
    const int last_tag = __builtin_amdgcn_readfirstlane(bi);

    // prefill tags[t] = last_tag for t in [L, T)
    for (int t = L + tid; t < T_DIM; t += 64) tags[t] = (unsigned char)last_tag;

    // serial backtrace: for t = thi..1: tags[t] = y; y = bp[t][y];  then tags[0] = y
    int y = last_tag;  // wave-uniform
    for (int c0 = (thi >> 6) << 6; c0 >= 0; c0 -= 64) {
        int row[64];   // row[k] holds bp[c0+k][jj] in lane jj
#pragma unroll
        for (int k = 0; k < 64; ++k) row[k] = bp[(c0 + k) * BPS + jj];

        int vacc = 0;
#pragma unroll
        for (int k = 63; k >= 0; --k) {
            const int t = c0 + k;
            vacc = (tid == k) ? y : vacc;                        // tags[t] = y (lane k)
            const int ynew = READLANE_I(row[k], y);
            if ((unsigned)(t - 1) < (unsigned)thi) y = ynew;     // update only t in [1, thi]
        }
        const int tk = c0 + tid;
        if (tk <= thi) tags[tk] = (unsigned char)(vacc & 0xff);
    }
    __syncthreads();   // phase boundary

    // emit one-hot: 4 rows (t) per iteration, 48 lanes x float4 = 768B coalesced
    if (tid < C_DIM) {
        const int r = tid / 12;          // row-in-group 0..3
        const int q = tid - r * 12;      // float4 slot 0..11
        const int cbase = q * 4;
        float* ob = out + (size_t)b * (T_DIM * C_DIM);
        for (int t0 = 0; t0 < T_DIM; t0 += 4) {
            const unsigned int tg4 = *(const unsigned int*)&tags[t0];
            const int mytag = (int)((tg4 >> (r * 8)) & 0xffu);
            float4 v;
            v.x = (cbase + 0 == mytag) ? 1.0f : 0.0f;
            v.y = (cbase + 1 == mytag) ? 1.0f : 0.0f;
            v.z = (cbase + 2 == mytag) ? 1.0f : 0.0f;
            v.w = (cbase + 3 == mytag) ? 1.0f : 0.0f;
            *(float4*)(ob + (size_t)(t0 + r) * C_DIM + cbase) = v;
        }
    }
}

extern "C" void kernel_launch(void* const* d_in, const int* in_sizes, int n_in,
                              void* d_out, int out_size, void* d_ws, size_t ws_size,
                              hipStream_t stream) {
    const float* pot    = (const float*)d_in[0];
    const int*   sl     = (const int*)d_in[1];
    const float* trans  = (const float*)d_in[2];
    float*       out    = (float*)d_out;
    const int B = in_sizes[1];  // sequence_lengths has B elements
    crf_viterbi<<<B, 64, 0, stream>>>(pot, sl, trans, out);
}

// Round 10
// 299.235 us; speedup vs baseline: 1.0309x; 1.0309x over previous
//
#include <hip/hip_runtime.h>

#define T_DIM 512
#define C_DIM 48
#define BPS   48          // bp row stride; 16-lane spill into next row is benign (see store)
#define CH    4           // global-prefetch / mask-precompute chunk

#if __has_builtin(__builtin_amdgcn_readlane)
#define READLANE_I(v, l) __builtin_amdgcn_readlane((v), (l))
#else
#define READLANE_I(v, l) __shfl((v), (l), 64)
#endif

// Compiler-level ordering fence for single-wave LDS communication.
#if __has_builtin(__builtin_amdgcn_wave_barrier)
#define WAVE_SYNC() do { __asm__ __volatile__("" ::: "memory"); __builtin_amdgcn_wave_barrier(); } while (0)
#else
#define WAVE_SYNC() __asm__ __volatile__("" ::: "memory")
#endif

__device__ __forceinline__ unsigned umin_(unsigned a, unsigned b) { return a < b ? a : b; }
__device__ __forceinline__ float max3f(float a, float b, float c) {
    float d;
    asm("v_max3_f32 %0, %1, %2, %3" : "=v"(d) : "v"(a), "v"(b), "v"(c));
    return d;
}
__device__ __forceinline__ unsigned min3u(unsigned a, unsigned b, unsigned c) {
    unsigned d;
    asm("v_min3_u32 %0, %1, %2, %3" : "=v"(d) : "v"(a), "v"(b), "v"(c));
    return d;
}

// One DPP max-reduce step: lanes with invalid source keep their own value
// (old = v, bound_ctrl = false), so max semantics are preserved.
#define DPP_MAX_STEP(V_, CTRL_) do {                                          \
    int o_ = __builtin_amdgcn_update_dpp(__float_as_int(V_),                  \
                                         __float_as_int(V_),                  \
                                         (CTRL_), 0xF, 0xF, false);           \
    V_ = fmaxf(V_, __int_as_float(o_));                                       \
} while (0)

// Full-wave f32 max (VALU-only): row_shr 1/2/4/8, row_bcast:15, row_bcast:31.
// Lanes 48-63 duplicate lane 47 in all uses here (harmless for max).
__device__ __forceinline__ float wave_max_f(float v) {
    DPP_MAX_STEP(v, 0x111);
    DPP_MAX_STEP(v, 0x112);
    DPP_MAX_STEP(v, 0x114);
    DPP_MAX_STEP(v, 0x118);
    DPP_MAX_STEP(v, 0x142);
    DPP_MAX_STEP(v, 0x143);
    return __int_as_float(READLANE_I(__float_as_int(v), 63));
}

__global__ __launch_bounds__(64) void crf_viterbi(
    const float* __restrict__ pot,     // [B][T][C]
    const int*   __restrict__ seqlen,  // [B][1]
    const float* __restrict__ trans,   // [C][C]
    float*       __restrict__ out)     // [B][T][C] one-hot f32
{
    const int b   = blockIdx.x;
    const int tid = threadIdx.x;
    const int jj  = (tid < C_DIM) ? tid : (C_DIM - 1);  // clamped for safe loads

    __shared__ __align__(16) float trl[C_DIM * C_DIM];   // transitions, row-major
    __shared__ unsigned char bp[T_DIM * BPS];            // rows 1..L-1 used
    __shared__ __align__(4) unsigned char tags[T_DIM];
    __shared__ __align__(16) float fsc[64];              // final scores

    const float* potb = pot + (size_t)b * (T_DIM * C_DIM);
    const int L   = seqlen[b];          // in [1, 511]
    const int thi = L - 1;

    // ---- stage transitions into LDS (coalesced) + tmax = max|Tr| ----
    float tm = 0.0f;
    for (int i = tid; i < C_DIM * C_DIM; i += 64) {      // 36 iters exactly
        float v = trans[i];
        trl[i] = v;
        tm = fmaxf(tm, fabsf(v));
    }
    const float tmax = wave_max_f(tm);                   // uniform
    const float nC5 = -(5.0f * tmax + 1e-3f);            // candidate window
    WAVE_SYNC();                                         // trl visible (same wave)

    // ---- init: lane j holds s(0)[j] = pot[0][j]; prow = pot row (t-1) ----
    float ns   = potb[jj];
    float prow = ns;

    const float* pp = potb + jj;

    float pb[CH];
#pragma unroll
    for (int k = 0; k < CH; ++k) {
        int tt = 1 + k; if (tt > T_DIM - 1) tt = T_DIM - 1;
        pb[k] = pp[tt * C_DIM];
    }

    for (int t0 = 1; t0 < L; t0 += CH) {
        float nb[CH];
#pragma unroll
        for (int k = 0; k < CH; ++k) {
            int tt = t0 + CH + k; if (tt > T_DIM - 1) tt = T_DIM - 1;
            nb[k] = pp[tt * C_DIM];
        }

        // ==== input-only phase: masks, candidate indices, trl loads ====
        // Candidates for step t depend ONLY on pot row t-1:
        //   true winner i* has s_i* >= s_max - 2tmax  ==>  pot_i* >= pmax - 4tmax
        //   (since per-column maxes m_j differ by <= 2tmax). Window 5tmax+1e-3
        //   gives a proven superset; fp error on O(5) values ~1e-6 << slack.
        int   cs[CH][4];
        float gv[CH][4];
        unsigned long long rem[CH];
#pragma unroll
        for (int k = 0; k < CH; ++k) {
            const float row = (k == 0) ? prow : pb[k - 1];   // pot row t0+k-1
            const float pm  = wave_max_f(row);
            unsigned long long mk =
                __ballot(row >= pm + nC5) & 0x0000FFFFFFFFFFFFull;
            if (!mk) mk = 0x0000FFFFFFFFFFFFull;             // defensive
            const int c0 = (int)__builtin_ctzll(mk);
            const unsigned long long m1 = mk & (mk - 1);
            const int c1 = m1 ? (int)__builtin_ctzll(m1) : c0;
            const unsigned long long m2 = m1 & (m1 - 1);
            const int c2 = m2 ? (int)__builtin_ctzll(m2) : c1;
            const unsigned long long m3 = m2 & (m2 - 1);
            const int c3 = m3 ? (int)__builtin_ctzll(m3) : c2;
            rem[k] = m3 & (m3 - 1);
            cs[k][0] = c0; cs[k][1] = c1; cs[k][2] = c2; cs[k][3] = c3;
            gv[k][0] = trl[c0 * C_DIM + jj];
            gv[k][1] = trl[c1 * C_DIM + jj];
            gv[k][2] = trl[c2 * C_DIM + jj];
            gv[k][3] = trl[c3 * C_DIM + jj];
        }

        // ==== serial recurrence: readlane -> add -> max tree -> ns ====
#pragma unroll
        for (int k = 0; k < CH; ++k) {
            const int t = t0 + k;
            if (t >= L) break;           // wave-uniform branch
            const float s0 = __int_as_float(READLANE_I(__float_as_int(ns), cs[k][0]));
            const float s1 = __int_as_float(READLANE_I(__float_as_int(ns), cs[k][1]));
            const float s2 = __int_as_float(READLANE_I(__float_as_int(ns), cs[k][2]));
            const float s3 = __int_as_float(READLANE_I(__float_as_int(ns), cs[k][3]));
            const float v0 = s0 + gv[k][0];              // exact same add as ref
            const float v1 = s1 + gv[k][1];
            const float v2 = s2 + gv[k][2];
            const float v3 = s3 + gv[k][3];
            const float mx4 = fmaxf(max3f(v0, v1, v2), v3);
            float mx = mx4;
            // index encode (off the recurrence): bits(v-mx)|c is c for the
            // max-tier (+0.0 -> 0), >=2^31 otherwise; min -> lowest index ==
            // first-occurrence argmax (validated R3/R8 trick). Duplicate-padded
            // candidates tie and lose. Result <= 47.
            const unsigned u0 = __float_as_uint(v0 - mx4) | (unsigned)cs[k][0];
            const unsigned u1 = __float_as_uint(v1 - mx4) | (unsigned)cs[k][1];
            const unsigned u2 = __float_as_uint(v2 - mx4) | (unsigned)cs[k][2];
            const unsigned u3 = __float_as_uint(v3 - mx4) | (unsigned)cs[k][3];
            int wi = (int)umin_(min3u(u0, u1, u2), u3);
            unsigned long long rr = rem[k];
            while (rr) {                                 // rare (>4 candidates)
                int c = (int)__builtin_ctzll(rr); rr &= rr - 1;
                float s = __int_as_float(READLANE_I(__float_as_int(ns), c));
                float cv = s + trl[c * C_DIM + jj];
                if (cv > mx) { mx = cv; wi = c; }        // strict: higher idx loses ties
            }
            // bp store: all 64 lanes; lanes 48-63 spill into row t+1 cols 0-15,
            // overwritten next step (or row thi+1 <= 511: never read).
            bp[t * BPS + tid] = (unsigned char)wi;
            ns = mx + pb[k];                             // exact same add as ref
        }
        prow = pb[CH - 1];
#pragma unroll
        for (int k = 0; k < CH; ++k) pb[k] = nb[k];
    }

    // publish final scores
    fsc[tid] = ns;
    WAVE_SYNC();
    __syncthreads();   // phase boundary (single wave; cheap)

    // last_tag = argmax over final scores (uniform LDS reads, broadcast)
    const float* fs = fsc;
    float bv = fs[0];
    int   bi = 0;
#pragma unroll
    for (int i = 1; i < C_DIM; ++i) {
        float v = fs[i];
        if (v > bv) { bv = v; bi = i; }
    }
    const int last_tag = __builtin_amdgcn_readfirstlane(bi);

    // prefill tags[t] = last_tag for t in [L, T)
    for (int t = L + tid; t < T_DIM; t += 64) tags[t] = (unsigned char)last_tag;

    // serial backtrace: for t = thi..1: tags[t] = y; y = bp[t][y];  then tags[0] = y
    int y = last_tag;  // wave-uniform
    for (int c0 = (thi >> 6) << 6; c0 >= 0; c0 -= 64) {
        int row[64];   // row[k] holds bp[c0+k][jj] in lane jj
#pragma unroll
        for (int k = 0; k < 64; ++k) row[k] = bp[(c0 + k) * BPS + jj];

        int vacc = 0;
#pragma unroll
        for (int k = 63; k >= 0; --k) {
            const int t = c0 + k;
            vacc = (tid == k) ? y : vacc;                        // tags[t] = y (lane k)
            const int ynew = READLANE_I(row[k], y);
            if ((unsigned)(t - 1) < (unsigned)thi) y = ynew;     // update only t in [1, thi]
        }
        const int tk = c0 + tid;
        if (tk <= thi) tags[tk] = (unsigned char)(vacc & 0xff);
    }
    __syncthreads();   // phase boundary

    // emit one-hot: 4 rows (t) per iteration, 48 lanes x float4 = 768B coalesced
    if (tid < C_DIM) {
        const int r = tid / 12;          // row-in-group 0..3
        const int q = tid - r * 12;      // float4 slot 0..11
        const int cbase = q * 4;
        float* ob = out + (size_t)b * (T_DIM * C_DIM);
        for (int t0 = 0; t0 < T_DIM; t0 += 4) {
            const unsigned int tg4 = *(const unsigned int*)&tags[t0];
            const int mytag = (int)((tg4 >> (r * 8)) & 0xffu);
            float4 v;
            v.x = (cbase + 0 == mytag) ? 1.0f : 0.0f;
            v.y = (cbase + 1 == mytag) ? 1.0f : 0.0f;
            v.z = (cbase + 2 == mytag) ? 1.0f : 0.0f;
            v.w = (cbase + 3 == mytag) ? 1.0f : 0.0f;
            *(float4*)(ob + (size_t)(t0 + r) * C_DIM + cbase) = v;
        }
    }
}

extern "C" void kernel_launch(void* const* d_in, const int* in_sizes, int n_in,
                              void* d_out, int out_size, void* d_ws, size_t ws_size,
                              hipStream_t stream) {
    const float* pot    = (const float*)d_in[0];
    const int*   sl     = (const int*)d_in[1];
    const float* trans  = (const float*)d_in[2];
    float*       out    = (float*)d_out;
    const int B = in_sizes[1];  // sequence_lengths has B elements
    crf_viterbi<<<B, 64, 0, stream>>>(pot, sl, trans, out);
}